// Round 10
// baseline (365.600 us; speedup 1.0000x reference)
//
#include <hip/hip_runtime.h>
#include <hip/hip_fp16.h>

#define BB 512
#define TT 2048
#define CH 128                // steps per LDS chunk (round 10: was 64)
#define NCH (TT/CH)           // 16 chunks

typedef _Float16 half2v __attribute__((ext_vector_type(2)));

// ---------- fast math helpers ----------
__device__ __forceinline__ float fexp2(float x){ return __builtin_amdgcn_exp2f(x); }
__device__ __forceinline__ float frcp(float x){ return __builtin_amdgcn_rcpf(x); }

#define QB(v, ctrl) __int_as_float(__builtin_amdgcn_mov_dpp(__float_as_int(v), (ctrl), 0xF, 0xF, true))
#define RL(v, l)    __builtin_amdgcn_readlane((v), (l))

// ---------- fused producer/consumer, round 10: CH 64 -> 128 ----------
// Single variable vs round 9 (236us, = round-6 best 235us): chunk size doubled.
// The unexplained +35 cy/step residual over the bare 240-cy chain did not respond
// to I$ shrink (r7/8), setprio (r7/8: -50us), or producer load scheduling (r9).
// Remaining suspects are all PER-CHUNK fixed costs (chunk-entry lgkm wait on the
// batched ds_reads, output-store vmcnt drain at the barrier, barrier skew).
// CH=128 halves every per-chunk cost; per-step costs unchanged. This is both the
// discriminating experiment and the fix if the theory holds.
//   producer: each lane fills 2 tg rows (tgl and tgl+8) per chunk, sharing the
//             Wih row s_loads across both sub-tiles. Early XLOAD + reg rotate (r9).
//   consumer: 16 rows read upfront (round-6 batch form scaled), 128 STEPs/chunk.
//   LDS: 2 x 16 x 424 ushort = 27,136 B.  NO setprio.
__global__ __launch_bounds__(128, 1) void k_pc5(
    const float* __restrict__ x,
    const float* __restrict__ Wih,
    const float* __restrict__ Whh,
    const float* __restrict__ bih,
    const float* __restrict__ bhh,
    const float* __restrict__ fcw,
    const float* __restrict__ fcb,
    float* __restrict__ out)
{
  __shared__ unsigned short xgb[2][16][424];   // [buf][tg][53 rows x 8 u]

  const int tid  = threadIdx.x;
  const int wid  = tid >> 6;
  const int lane = tid & 63;
  const int b    = blockIdx.x;

  // ---- producer state (persists across chunk loop)
  float xrA0[13], xrA1[13], xrB0[13], xrB1[13];
  const int  tgl = lane >> 3, u = lane & 7;
  // chunk c, tg row r covers t = c*128 + r*8 + u; lane owns r = tgl and r = tgl+8
  const float* xbase = x + ((size_t)b*TT + tgl*8 + u)*13;
  unsigned short fc16 = 0;

  // ---- consumer state (persists across chunk loop; k_rec7 verbatim)
  float w[13];
  float gm = 1.f, ga = 0.f, fcbias = 0.f;
  int   e = 0;
  float h = 0.f, c_ = 0.f;            // c_ carries -2*log2e*c
  float hb0=0,hb1=0,hb2=0,hb3=0,hb4=0,hb5=0,hb6=0,hb7=0,hb8=0,hb9=0,hb10=0,hb11=0,hb12=0;
  float p0=0,p1=0,p2=0,p3=0,p4=0,p5=0,p6=0,p7=0;
  float* op = out + (size_t)b*TT;
  bool first = true;

// producer: issue chunk c_'s 26 coalesced per-lane dwords (two 8-row halves)
// into register sets XR0/XR1, BEFORE FILL so HBM latency hides under FMA work.
#define XLOADB(c_, XR0, XR1) do {                                             \
    const float* p_  = xbase + (size_t)(c_)*(CH*13);                          \
    const float* p2_ = p_ + 64*13;                                            \
    _Pragma("unroll")                                                         \
    for (int k=0;k<13;++k) XR0[k] = p_[k];                                    \
    _Pragma("unroll")                                                         \
    for (int k=0;k<13;++k) XR1[k] = p2_[k];                                   \
  } while(0)

// rotate register double-buffer: A <- B (vmcnt wait absorbed here)
#define PROT() do {                                                           \
    _Pragma("unroll")                                                         \
    for (int k=0;k<13;++k){ xrA0[k] = xrB0[k]; xrA1[k] = xrB1[k]; }           \
  } while(0)

// producer: compute + write one chunk (both tg halves; Wih row shared per g).
// unroll 4 (round-6 form; round 7 proved unroll 1 regresses via s_load latency).
#define FILL(bi_) do {                                                        \
    unsigned short* dst0_ = &xgb[bi_][tgl  ][0];                              \
    unsigned short* dst1_ = &xgb[bi_][tgl+8][0];                              \
    _Pragma("unroll 4")                                                       \
    for (int g=0; g<52; ++g){                                                 \
      const float bs_ = bih[g] + bhh[g];                                      \
      float acc0 = bs_, acc1 = bs_;                                           \
      _Pragma("unroll")                                                       \
      for (int k=0;k<13;++k){                                                 \
        const float wv_ = Wih[g*13+k];                                        \
        acc0 = fmaf(wv_, xrA0[k], acc0);                                      \
        acc1 = fmaf(wv_, xrA1[k], acc1);                                      \
      }                                                                       \
      const float sc = (g>=26 && g<39) ? -2.8853900817779268f                 \
                                       : -1.4426950408889634f;                \
      dst0_[g*8 + u] = __half_as_ushort(__float2half(acc0*sc));               \
      dst1_[g*8 + u] = __half_as_ushort(__float2half(acc1*sc));               \
    }                                                                         \
    dst0_[52*8 + u] = fc16;                                                   \
    dst1_[52*8 + u] = fc16;                                                   \
  } while(0)

#define CAPTURE(gv_, u_) do {                                                 \
    if ((u_)==1) p0=(gv_); else if ((u_)==2) p1=(gv_);                        \
    else if ((u_)==3) p2=(gv_); else if ((u_)==4) p3=(gv_);                   \
    else if ((u_)==5) p4=(gv_); else if ((u_)==6) p5=(gv_);                   \
    else if ((u_)==7) p6=(gv_);                                               \
    else { p7=(gv_);                                                          \
      if (!first){                                                            \
        if (lane == 52){                                                      \
          float4* o4 = (float4*)op;                                           \
          o4[0] = make_float4(p0,p1,p2,p3);                                   \
          o4[1] = make_float4(p4,p5,p6,p7);                                   \
        }                                                                     \
        op += 8;                                                              \
      }                                                                       \
      first = false;                                                          \
    }                                                                         \
  } while(0)

#define STEP(xv_, u_) do {                                                    \
    float dA = fmaf(w[0], hb0, (xv_));                                        \
    dA = fmaf(w[1], hb1, dA);                                                 \
    dA = fmaf(w[2], hb2, dA);                                                 \
    dA = fmaf(w[3], hb3, dA);                                                 \
    dA = fmaf(w[4], hb4, dA);                                                 \
    float dB = w[5]*hb5;                                                      \
    dB = fmaf(w[6], hb6, dB);                                                 \
    dB = fmaf(w[7], hb7, dB);                                                 \
    dB = fmaf(w[8], hb8, dB);                                                 \
    float dC = w[9]*hb9;                                                      \
    dC = fmaf(w[10], hb10, dC);                                               \
    dC = fmaf(w[11], hb11, dC);                                               \
    dC = fmaf(w[12], hb12, dC);                                               \
    float s  = (dB + dC) + dA;                                                \
    float r  = frcp(1.f + fexp2(s));                                          \
    float g  = fmaf(gm, r, ga);                                               \
    CAPTURE(g, u_);                                                           \
    float ggb = QB(g, 0xAA);                                                  \
    float gfb = QB(g, 0x55);                                                  \
    float gob = QB(g, 0xFF);                                                  \
    float go2 = gob + gob;                                                    \
    c_ = fmaf(gfb, c_, g*ggb);                                                \
    float r2 = frcp(1.f + fexp2(c_));                                         \
    h = fmaf(go2, r2, -gob);                                                  \
    int hv_ = __float_as_int(h);                                              \
    hb0  = __int_as_float(RL(hv_, 0));                                        \
    hb1  = __int_as_float(RL(hv_, 4));                                        \
    hb2  = __int_as_float(RL(hv_, 8));                                        \
    hb3  = __int_as_float(RL(hv_, 12));                                       \
    hb4  = __int_as_float(RL(hv_, 16));                                       \
    hb5  = __int_as_float(RL(hv_, 20));                                       \
    hb6  = __int_as_float(RL(hv_, 24));                                       \
    hb7  = __int_as_float(RL(hv_, 28));                                       \
    hb8  = __int_as_float(RL(hv_, 32));                                       \
    hb9  = __int_as_float(RL(hv_, 36));                                       \
    hb10 = __int_as_float(RL(hv_, 40));                                       \
    hb11 = __int_as_float(RL(hv_, 44));                                       \
    hb12 = __int_as_float(RL(hv_, 48));                                       \
  } while(0)

#define XLO(w_) (float)(__builtin_bit_cast(half2v, (w_)).x)
#define XHI(w_) (float)(__builtin_bit_cast(half2v, (w_)).y)

#define STEP8(Q) do {                                                         \
    STEP(XLO(Q.x), 0); STEP(XHI(Q.x), 1);                                     \
    STEP(XLO(Q.y), 2); STEP(XHI(Q.y), 3);                                     \
    STEP(XLO(Q.z), 4); STEP(XHI(Q.z), 5);                                     \
    STEP(XLO(Q.w), 6); STEP(XHI(Q.w), 7);                                     \
  } while(0)

// consumer: one chunk = 16 tg rows, batch-read upfront (round-6 form scaled)
#define CONSUME(bi_) do {                                                     \
    const char* base_ = (const char*)&xgb[bi_][0][0] + (size_t)e*16;          \
    uint4 r0  = *(const uint4*)(base_ +  0*848);                              \
    uint4 r1  = *(const uint4*)(base_ +  1*848);                              \
    uint4 r2  = *(const uint4*)(base_ +  2*848);                              \
    uint4 r3  = *(const uint4*)(base_ +  3*848);                              \
    uint4 r4  = *(const uint4*)(base_ +  4*848);                              \
    uint4 r5  = *(const uint4*)(base_ +  5*848);                              \
    uint4 r6  = *(const uint4*)(base_ +  6*848);                              \
    uint4 r7  = *(const uint4*)(base_ +  7*848);                              \
    uint4 r8  = *(const uint4*)(base_ +  8*848);                              \
    uint4 r9  = *(const uint4*)(base_ +  9*848);                              \
    uint4 r10 = *(const uint4*)(base_ + 10*848);                              \
    uint4 r11 = *(const uint4*)(base_ + 11*848);                              \
    uint4 r12 = *(const uint4*)(base_ + 12*848);                              \
    uint4 r13 = *(const uint4*)(base_ + 13*848);                              \
    uint4 r14 = *(const uint4*)(base_ + 14*848);                              \
    uint4 r15 = *(const uint4*)(base_ + 15*848);                              \
    STEP8(r0);  STEP8(r1);  STEP8(r2);  STEP8(r3);                            \
    STEP8(r4);  STEP8(r5);  STEP8(r6);  STEP8(r7);                            \
    STEP8(r8);  STEP8(r9);  STEP8(r10); STEP8(r11);                           \
    STEP8(r12); STEP8(r13); STEP8(r14); STEP8(r15);                           \
  } while(0)

  if (wid == 1){
    // -------- producer setup + chunk 0 --------
    fc16 = __half_as_ushort(__float2half(-1.4426950408889634f * fcb[0]));
    XLOADB(0, xrA0, xrA1);    // chunk 0 raw x
    XLOADB(1, xrB0, xrB1);    // chunk 1 in flight during FILL(0)
    FILL(0);                  // sx chunk 0 (from xrA)
    PROT();                   // xrA <- xrB (chunk 1; loads landed during FILL)
  } else {
    // -------- consumer setup (k_rec7 verbatim; NO setprio) --------
    const int q  = lane & 3;
    const int j  = lane >> 2;             // 0..15 (13..15 padding)
    const int jc = (j < 13) ? j : 12;
    e = (lane == 52) ? 52 : q*13 + jc;
    const float kq = (q==2) ? -2.8853900817779268f : -1.4426950408889634f;
    gm = (q==2) ? -5.7707801635558536f : 1.f;
    ga = (q==2) ?  2.8853900817779268f : 0.f;
    fcbias = -1.4426950408889634f * fcb[0];
    const float* wsrc = (lane == 52) ? fcw : (Whh + (size_t)e*13);
    #pragma unroll
    for (int k=0;k<13;k++) w[k] = wsrc[k]*kq;
  }
  __syncthreads();                                  // chunk 0 ready

  for (int c=0; c<NCH-1; ++c){
    if (wid == 1){
      if (c < NCH-2) XLOADB(c+2, xrB0, xrB1);       // issue EARLY: lands during FILL
      FILL((c+1)&1);                                // chunk c+1 (from xrA)
      PROT();                                       // xrA <- xrB (wait absorbed here)
    } else {
      CONSUME(c&1);                                 // chunk c
    }
    __syncthreads();                                // chunk c+1 ready
  }

  if (wid == 0){
    CONSUME((NCH-1)&1);                             // chunk 15

    // epilogue: out[2047] = sigmoid(fc_b + fc_w·h_2047); lane 52 stores p0..p6 + r
    float s = fcbias;
    s = fmaf(w[0],  hb0,  s);
    s = fmaf(w[1],  hb1,  s);
    s = fmaf(w[2],  hb2,  s);
    s = fmaf(w[3],  hb3,  s);
    s = fmaf(w[4],  hb4,  s);
    s = fmaf(w[5],  hb5,  s);
    s = fmaf(w[6],  hb6,  s);
    s = fmaf(w[7],  hb7,  s);
    s = fmaf(w[8],  hb8,  s);
    s = fmaf(w[9],  hb9,  s);
    s = fmaf(w[10], hb10, s);
    s = fmaf(w[11], hb11, s);
    s = fmaf(w[12], hb12, s);
    float r = frcp(1.f + fexp2(s));
    if (lane == 52){
      float4* o4 = (float4*)op;                     // op == out + b*TT + 2040 here
      o4[0] = make_float4(p0,p1,p2,p3);
      o4[1] = make_float4(p4,p5,p6,r);
    }
  }

#undef CONSUME
#undef STEP8
#undef STEP
#undef CAPTURE
#undef FILL
#undef PROT
#undef XLOADB
#undef XLO
#undef XHI
}

extern "C" void kernel_launch(void* const* d_in, const int* in_sizes, int n_in,
                              void* d_out, int out_size, void* d_ws, size_t ws_size,
                              hipStream_t stream)
{
  const float* x   = (const float*)d_in[0];
  const float* Wih = (const float*)d_in[1];
  const float* Whh = (const float*)d_in[2];
  const float* bih = (const float*)d_in[3];
  const float* bhh = (const float*)d_in[4];
  const float* fcw = (const float*)d_in[5];
  const float* fcb = (const float*)d_in[6];
  float* out = (float*)d_out;

  (void)d_ws; (void)ws_size;   // fully fused: no workspace
  k_pc5<<<dim3(BB), dim3(128), 0, stream>>>(x, Wih, Whh, bih, bhh, fcw, fcb, out);
}